// Round 11
// baseline (445.669 us; speedup 1.0000x reference)
//
#include <hip/hip_runtime.h>
#include <hip/hip_bf16.h>
#include <math.h>

#define NF 1433
#define NH 16
#define NC 7
#define NCH 45          // ceil(1433/32) 32-col sub-chunks (Wb layout)
#define NFC 22          // full 64-col LDS chunks (cols 0..1407); tail via regs
#define NBKT_MAX 512    // supports n <= 131072 (bucket = dst>>8)
#define SC_C 3072       // edges per bscatter block (LDS-sortable chunk)

typedef __attribute__((ext_vector_type(8))) short bf16x8;
typedef __attribute__((ext_vector_type(4))) float f32x4;

__device__ __forceinline__ unsigned short f2bf(float f) {
  unsigned int u = __float_as_uint(f);
  unsigned int r = (u + 0x7FFFu + ((u >> 16) & 1u)) >> 16;  // RNE
  return (unsigned short)r;
}
// hot-path convert (compiler folds pairs into v_cvt_pk_bf16_f32)
__device__ __forceinline__ short f2bfs(float f) {
  union { __hip_bfloat16 h; short s; } u;
  u.h = __float2bfloat16(f);
  return u.s;
}
__device__ __forceinline__ unsigned int packbf(float lo, float hi) {
  return (unsigned int)f2bf(lo) | ((unsigned int)f2bf(hi) << 16);
}
// accumulate 8 bf16 (packed in uint4) into a[0..7]
__device__ __forceinline__ void acc8(float* a, uint4 r) {
  a[0] += __uint_as_float(r.x << 16); a[1] += __uint_as_float(r.x & 0xffff0000u);
  a[2] += __uint_as_float(r.y << 16); a[3] += __uint_as_float(r.y & 0xffff0000u);
  a[4] += __uint_as_float(r.z << 16); a[5] += __uint_as_float(r.z & 0xffff0000u);
  a[6] += __uint_as_float(r.w << 16); a[7] += __uint_as_float(r.w & 0xffff0000u);
}

// async global->LDS DMA, 4B/lane: LDS dest is wave-uniform base + lane*4,
// global src is per-lane (m104/m108 contract).
#define GLOAD(gp, lp) __builtin_amdgcn_global_load_lds(                     \
    (const __attribute__((address_space(1))) void*)(gp),                    \
    (__attribute__((address_space(3))) void*)(lp), 4, 0, 0)

// ---------------- W1 fragment pack + bcnt zero (fused, independent work) ----
// Wb[(c*64 + lane)*8 + i] = bf16(W1[k][col]), k = c*32 + (lane>>4)*8 + i, col = lane&15
__global__ void k_wpack_zero(const float* __restrict__ W1, short* __restrict__ Wb,
                             int* __restrict__ bcnt) {
  int t = blockIdx.x * blockDim.x + threadIdx.x;
  if (t < 16 * NBKT_MAX) bcnt[t] = 0;
  if (t >= NCH * 64 * 8) return;
  int i = t & 7, l = (t >> 3) & 63, c = t >> 9;
  int g = l >> 4, col = l & 15;
  int k = c * 32 + g * 8 + i;
  float v = (k < NF) ? W1[(size_t)k * NH + col] : 0.f;
  Wb[t] = (short)f2bf(v);
}

// ---------------- bucketed CSR build ----------------
__global__ __launch_bounds__(256) void k_bcount(const int* __restrict__ dst,
                                                int* __restrict__ bcnt,
                                                int E, int nbkt) {
  __shared__ int h[NBKT_MAX];
  int t = threadIdx.x;
  for (int i = t; i < nbkt; i += 256) h[i] = 0;
  __syncthreads();
  int e0 = blockIdx.x * SC_C;
  int e1 = min(E, e0 + SC_C);
  for (int e = e0 + t; e < e1; e += 256)
    atomicAdd(&h[((unsigned)dst[e]) >> 8], 1);
  __syncthreads();
  for (int i = t; i < nbkt; i += 256)
    if (h[i]) atomicAdd(&bcnt[i * 16], h[i]);
}

__global__ void k_bscan(const int* __restrict__ bcnt, int* __restrict__ bbase,
                        int* __restrict__ bfill, int nbkt) {
  __shared__ int sm[NBKT_MAX];
  int t = threadIdx.x;  // blockDim = NBKT_MAX
  int v = (t < nbkt) ? bcnt[t * 16] : 0;
  sm[t] = v;
  __syncthreads();
  for (int o = 1; o < NBKT_MAX; o <<= 1) {
    int u = (t >= o) ? sm[t - o] : 0;
    __syncthreads();
    sm[t] += u;
    __syncthreads();
  }
  if (t < nbkt) {
    int b = sm[t] - v;
    bbase[t] = b;
    bfill[t * 16] = b;
  }
  if (t == nbkt) bbase[nbkt] = sm[t];  // == E
}

__global__ __launch_bounds__(256) void k_bscatter(const int* __restrict__ ei,
                                                  int* __restrict__ bfill,
                                                  int* __restrict__ ebuf,
                                                  int E, int nbkt) {
  __shared__ int h[NBKT_MAX];              // hist, then fill cursor
  __shared__ int lo[NBKT_MAX];             // block-local exclusive base
  __shared__ int lb[NBKT_MAX];             // reserved global base
  __shared__ int sc2[256];
  __shared__ int sval[SC_C];
  __shared__ unsigned short sbkt[SC_C];
  const int* src = ei;
  const int* dst = ei + E;
  int t = threadIdx.x;
  for (int i = t; i < NBKT_MAX; i += 256) h[i] = 0;
  __syncthreads();
  int e0 = blockIdx.x * SC_C;
  int e1 = min(E, e0 + SC_C);
  int csize = e1 - e0;
  for (int e = e0 + t; e < e1; e += 256)
    atomicAdd(&h[((unsigned)dst[e]) >> 8], 1);
  __syncthreads();
  int base = 0;
#pragma unroll
  for (int j = 0; j < 2; ++j) {
    int idx = j * 256 + t;
    int v = h[idx];
    sc2[t] = v;
    __syncthreads();
    for (int o = 1; o < 256; o <<= 1) {
      int u = (t >= o) ? sc2[t - o] : 0;
      __syncthreads();
      sc2[t] += u;
      __syncthreads();
    }
    lo[idx] = base + sc2[t] - v;
    int tot = sc2[255];
    __syncthreads();
    base += tot;
  }
  for (int i = t; i < nbkt; i += 256) {
    int c = h[i];
    lb[i] = c ? atomicAdd(&bfill[i * 16], c) : 0;
    h[i] = 0;
  }
  __syncthreads();
  for (int e = e0 + t; e < e1; e += 256) {
    unsigned d = (unsigned)dst[e];
    int bk = d >> 8;
    int p = lo[bk] + atomicAdd(&h[bk], 1);
    sval[p] = (int)(((d & 255u) << 24) | (unsigned)src[e]);
    sbkt[p] = (unsigned short)bk;
  }
  __syncthreads();
  for (int i = t; i < csize; i += 256) {
    int bk = sbkt[i];
    ebuf[lb[bk] + (i - lo[bk])] = sval[i];
  }
}

__global__ __launch_bounds__(256) void k_bcsr(const int* __restrict__ ebuf,
                                              const int* __restrict__ bbase,
                                              int* __restrict__ off,
                                              int* __restrict__ srcs,
                                              float* __restrict__ dis, int n) {
  __shared__ int h[256];
  __shared__ int sc[256];
  int b = blockIdx.x, t = threadIdx.x;
  int eb = bbase[b], ee = bbase[b + 1];
  h[t] = 0;
  __syncthreads();
  for (int i = eb + t; i < ee; i += 256)
    atomicAdd(&h[((unsigned)ebuf[i]) >> 24], 1);
  __syncthreads();
  int deg = h[t];
  sc[t] = deg;
  __syncthreads();
  for (int o = 1; o < 256; o <<= 1) {
    int u = (t >= o) ? sc[t - o] : 0;
    __syncthreads();
    sc[t] += u;
    __syncthreads();
  }
  int excl = sc[t] - deg;
  int node = (b << 8) + t;
  if (node < n) {
    off[node] = eb + excl;
    dis[node] = rsqrtf((float)deg + 1.0f);
  }
  if (b == (int)gridDim.x - 1 && t == 0) off[n] = ee;
  h[t] = eb + excl;  // reuse as fill cursor
  __syncthreads();
  for (int i = eb + t; i < ee; i += 256) {
    unsigned v = (unsigned)ebuf[i];
    int slot = atomicAdd(&h[v >> 24], 1);
    srcs[slot] = (int)(v & 0xFFFFFFu);
  }
}

// ---------------- GEMM1: async-DMA LDS staging, wave-private, no barriers ---
// hs1 = bf16( (x @ W1) * dis[row] ), [n][16] bf16 rows.
// Wave = 16 rows. Per 64-col chunk: 16 x global_load_lds (one per row; lane =
// col -> contiguous 256B per instruction), vmcnt(0), then 2 sub-chunks of
// {2x ds_read_b128, cvt, MFMA}. MLP from 32 waves/CU, each 4KB in flight.
__global__ __launch_bounds__(256) void k_gemm1(
    const float* __restrict__ x, const short* __restrict__ Wb,
    const float* __restrict__ dis, unsigned short* __restrict__ hs1, int n) {
  __shared__ float xs[4][16][68];   // [wave][row][col(+pad)]  17.4KB/block
  int l = threadIdx.x & 63;
  int wv = threadIdx.x >> 6;
  int wid = (blockIdx.x << 2) + wv;
  int ntb = (n + 15) >> 4;
  if (wid >= ntb) return;          // no barriers in this kernel -> safe
  int row0 = wid << 4;
  int rl = l & 15, g = l >> 4;
  bool fast = (row0 + 15 < n);     // n % 16 == 0 -> always true in practice

  const bf16x8* wp = (const bf16x8*)Wb + l;
  f32x4 acc;
#pragma unroll
  for (int j = 0; j < 4; ++j) acc[j] = 0.f;

  for (int c = 0; c < NFC; ++c) {
    // all prior ds_reads done before overwriting the buffer (single buffer)
    asm volatile("s_waitcnt lgkmcnt(0)" ::: "memory");
    if (fast) {
      const float* cb = x + (size_t)row0 * NF + c * 64 + l;
#pragma unroll
      for (int r = 0; r < 16; ++r)
        GLOAD(cb + (size_t)r * NF, &xs[wv][r][0]);
    } else {
#pragma unroll
      for (int r = 0; r < 16; ++r) {
        int rr = row0 + r;
        if (rr >= n) rr = n - 1;
        GLOAD(x + (size_t)rr * NF + c * 64 + l, &xs[wv][r][0]);
      }
    }
    asm volatile("s_waitcnt vmcnt(0)" ::: "memory");  // stage complete
#pragma unroll
    for (int ks = 0; ks < 2; ++ks) {
      bf16x8 w = wp[(size_t)(2 * c + ks) * 64];
      const float4* p = (const float4*)&xs[wv][rl][ks * 32 + g * 8];
      float4 a0 = p[0], a1 = p[1];
      bf16x8 af;
      af[0] = f2bfs(a0.x); af[1] = f2bfs(a0.y);
      af[2] = f2bfs(a0.z); af[3] = f2bfs(a0.w);
      af[4] = f2bfs(a1.x); af[5] = f2bfs(a1.y);
      af[6] = f2bfs(a1.z); af[7] = f2bfs(a1.w);
      acc = __builtin_amdgcn_mfma_f32_16x16x32_bf16(af, w, acc, 0, 0, 0);
    }
  }

  // K tail: cols 1408..1432 via guarded register loads (A row = lane&15)
  {
    int rr = row0 + rl;
    if (rr >= n) rr = n - 1;
    const float* xp = x + (size_t)rr * NF;
    bf16x8 wt = wp[(size_t)(NCH - 1) * 64];
    bf16x8 at;
#pragma unroll
    for (int i = 0; i < 8; ++i) {
      int k = NFC * 64 + g * 8 + i;
      at[i] = (k < NF) ? f2bfs(xp[k]) : (short)0;
    }
    acc = __builtin_amdgcn_mfma_f32_16x16x32_bf16(at, wt, acc, 0, 0, 0);
  }

  // D layout (m89): col = lane&15, row_in_tile = (lane>>4)*4 + reg
#pragma unroll
  for (int rr = 0; rr < 4; ++rr) {
    int row = row0 + g * 4 + rr;
    if (row < n) hs1[(size_t)row * NH + rl] = f2bf(acc[rr] * dis[row]);
  }
}

// ---------------- pull layer 1 + bias + relu + GEMM2 fused (16 lanes/node) --
__global__ __launch_bounds__(256) void k_pull1(
    const int* __restrict__ off, const int* __restrict__ srcs,
    const float* __restrict__ dis, const uint4* __restrict__ hs1,
    const float* __restrict__ b1, const float* __restrict__ W2,
    uint4* __restrict__ hs2, int n) {
  int t = blockIdx.x * blockDim.x + threadIdx.x;
  int d = t >> 4;
  if (d >= n) return;
  int sub = t & 15, half = sub & 1, ph = sub >> 1;  // ph in [0,8)

  float a[8] = {0.f, 0.f, 0.f, 0.f, 0.f, 0.f, 0.f, 0.f};
  if (ph == 0) acc8(a, hs1[(size_t)d * 2 + half]);  // self loop, once per half

  int k = off[d] + ph, k1 = off[d + 1];
  for (; k + 8 < k1; k += 16) {  // 2 independent gathers in flight
    int s0 = srcs[k], s1 = srcs[k + 8];
    uint4 r0 = hs1[(size_t)s0 * 2 + half];
    uint4 r1 = hs1[(size_t)s1 * 2 + half];
    acc8(a, r0);
    acc8(a, r1);
  }
  if (k < k1) acc8(a, hs1[(size_t)srcs[k] * 2 + half]);

#pragma unroll
  for (int i = 0; i < 8; ++i) {  // reduce over the 8 phases (lane bits 1..3)
    a[i] += __shfl_xor(a[i], 2);
    a[i] += __shfl_xor(a[i], 4);
    a[i] += __shfl_xor(a[i], 8);
  }

  float dd = dis[d];
  float v[8];
#pragma unroll
  for (int i = 0; i < 8; ++i) v[i] = fmaxf(a[i] * dd + b1[half * 8 + i], 0.f);
  float p[NC];
#pragma unroll
  for (int c = 0; c < NC; ++c) {
    float s = 0.f;
#pragma unroll
    for (int i = 0; i < 8; ++i) s = fmaf(v[i], W2[(half * 8 + i) * NC + c], s);
    p[c] = s;
  }
#pragma unroll
  for (int c = 0; c < NC; ++c) p[c] += __shfl_xor(p[c], 1);  // combine halves
  if (sub == 0) {
    uint4 o;
    o.x = packbf(p[0] * dd, p[1] * dd);
    o.y = packbf(p[2] * dd, p[3] * dd);
    o.z = packbf(p[4] * dd, p[5] * dd);
    o.w = packbf(p[6] * dd, 0.f);  // pad col
    hs2[d] = o;
  }
}

// ---------------- pull layer 2 + bias + relu + log_softmax (8 lanes/node) ---
__global__ __launch_bounds__(256) void k_pull2(
    const int* __restrict__ off, const int* __restrict__ srcs,
    const float* __restrict__ dis, const uint4* __restrict__ hs2,
    const float* __restrict__ b2, float* __restrict__ out, int n) {
  int t = blockIdx.x * blockDim.x + threadIdx.x;
  int d = t >> 3;
  if (d >= n) return;
  int ph = t & 7;

  float a[8] = {0.f, 0.f, 0.f, 0.f, 0.f, 0.f, 0.f, 0.f};
  if (ph == 0) acc8(a, hs2[d]);  // self loop once

  int k = off[d] + ph, k1 = off[d + 1];
  for (; k + 8 < k1; k += 16) {
    int s0 = srcs[k], s1 = srcs[k + 8];
    uint4 r0 = hs2[s0];
    uint4 r1 = hs2[s1];
    acc8(a, r0);
    acc8(a, r1);
  }
  if (k < k1) acc8(a, hs2[srcs[k]]);

#pragma unroll
  for (int i = 0; i < 8; ++i) {  // reduce across the 8 phase lanes
    a[i] += __shfl_xor(a[i], 1);
    a[i] += __shfl_xor(a[i], 2);
    a[i] += __shfl_xor(a[i], 4);
  }
  float dd = dis[d];
  float u[NC];
#pragma unroll
  for (int c = 0; c < NC; ++c) u[c] = fmaxf(a[c] * dd + b2[c], 0.f);
  float m = u[0];
#pragma unroll
  for (int c = 1; c < NC; ++c) m = fmaxf(m, u[c]);
  float sum = 0.f;
#pragma unroll
  for (int c = 0; c < NC; ++c) sum += expf(u[c] - m);
  float lg = logf(sum);
  if (ph < NC) out[(size_t)d * NC + ph] = u[ph] - m - lg;
}

extern "C" void kernel_launch(void* const* d_in, const int* in_sizes, int n_in,
                              void* d_out, int out_size, void* d_ws, size_t ws_size,
                              hipStream_t stream) {
  const float* x  = (const float*)d_in[0];
  const int*   ei = (const int*)d_in[1];
  const float* W1 = (const float*)d_in[2];
  const float* b1 = (const float*)d_in[3];
  const float* W2 = (const float*)d_in[4];
  const float* b2 = (const float*)d_in[5];
  int n = in_sizes[0] / NF;   // 100000
  int E = in_sizes[1] / 2;    // 3200000
  int nbkt = (n + 255) >> 8;  // 391

  // workspace layout (each region 16B-aligned)
  char* w = (char*)d_ws;
#define TAKE(ptrty, name, bytes) \
  ptrty name = (ptrty)w; w += ((size_t)(bytes) + 15) & ~(size_t)15;
  TAKE(unsigned short*, hs1,  sizeof(short) * (size_t)n * NH)
  TAKE(uint4*,          hs2,  16 * (size_t)n)
  TAKE(float*,          dis,  sizeof(float) * n)
  TAKE(short*,          Wb,   sizeof(short) * NCH * 64 * 8)
  TAKE(int*,            bcnt, sizeof(int) * 16 * NBKT_MAX)
  TAKE(int*,            bfill,sizeof(int) * 16 * NBKT_MAX)
  TAKE(int*,            bbase,sizeof(int) * (NBKT_MAX + 1))
  TAKE(int*,            ebuf, sizeof(int) * (size_t)E)
  TAKE(int*,            off,  sizeof(int) * (n + 1))
  TAKE(int*,            srcs, sizeof(int) * (size_t)E)
#undef TAKE
  float* out = (float*)d_out;

  int nsb = (E + SC_C - 1) / SC_C;  // 1042

  // independent prep (also zeroes bcnt)
  k_wpack_zero<<<(NCH * 64 * 8 + 255) / 256, 256, 0, stream>>>(W1, Wb, bcnt);

  // bucketed CSR build
  k_bcount<<<nsb, 256, 0, stream>>>(ei + E, bcnt, E, nbkt);
  k_bscan<<<1, NBKT_MAX, 0, stream>>>(bcnt, bbase, bfill, nbkt);
  k_bscatter<<<nsb, 256, 0, stream>>>(ei, bfill, ebuf, E, nbkt);
  k_bcsr<<<nbkt, 256, 0, stream>>>(ebuf, bbase, off, srcs, dis, n);

  // features — gemm1 launched TWICE (idempotent) as a self-measuring probe:
  // total = base + 2*g_new; next round drops the duplicate.
  int ntb = (n + 15) >> 4;  // 6250 wave-tiles
  int gblocks = (ntb + 3) / 4;
  k_gemm1<<<gblocks, 256, 0, stream>>>(x, Wb, dis, hs1, n);
  k_gemm1<<<gblocks, 256, 0, stream>>>(x, Wb, dis, hs1, n);
  k_pull1<<<((size_t)n * 16 + 255) / 256, 256, 0, stream>>>(
      off, srcs, dis, (const uint4*)hs1, b1, W2, hs2, n);
  k_pull2<<<((size_t)n * 8 + 255) / 256, 256, 0, stream>>>(
      off, srcs, dis, hs2, b2, out, n);
}

// Round 12
// 316.745 us; speedup vs baseline: 1.4070x; 1.4070x over previous
//
#include <hip/hip_runtime.h>
#include <hip/hip_bf16.h>
#include <math.h>

#define NF 1433
#define NH 16
#define NC 7
#define NCH 45          // ceil(1433/32) 32-col sub-chunks (Wb layout)
#define NFC 22          // full 64-col LDS chunks (cols 0..1407); tail via regs
#define NBKT_MAX 512    // supports n <= 131072 (bucket = dst>>8)
#define SC_C 3072       // edges per bscatter block (LDS-sortable chunk)

typedef __attribute__((ext_vector_type(8))) short bf16x8;
typedef __attribute__((ext_vector_type(4))) float f32x4;

__device__ __forceinline__ unsigned short f2bf(float f) {
  unsigned int u = __float_as_uint(f);
  unsigned int r = (u + 0x7FFFu + ((u >> 16) & 1u)) >> 16;  // RNE
  return (unsigned short)r;
}
// hot-path convert (compiler folds pairs into v_cvt_pk_bf16_f32)
__device__ __forceinline__ short f2bfs(float f) {
  union { __hip_bfloat16 h; short s; } u;
  u.h = __float2bfloat16(f);
  return u.s;
}
__device__ __forceinline__ unsigned int packbf(float lo, float hi) {
  return (unsigned int)f2bf(lo) | ((unsigned int)f2bf(hi) << 16);
}
// accumulate 8 bf16 (packed in uint4) into a[0..7]
__device__ __forceinline__ void acc8(float* a, uint4 r) {
  a[0] += __uint_as_float(r.x << 16); a[1] += __uint_as_float(r.x & 0xffff0000u);
  a[2] += __uint_as_float(r.y << 16); a[3] += __uint_as_float(r.y & 0xffff0000u);
  a[4] += __uint_as_float(r.z << 16); a[5] += __uint_as_float(r.z & 0xffff0000u);
  a[6] += __uint_as_float(r.w << 16); a[7] += __uint_as_float(r.w & 0xffff0000u);
}

// async global->LDS DMA, 4B/lane: LDS dest is wave-uniform base + lane*4,
// global src is per-lane (m104/m108 contract).
#define GLOAD(gp, lp) __builtin_amdgcn_global_load_lds(                     \
    (const __attribute__((address_space(1))) void*)(gp),                    \
    (__attribute__((address_space(3))) void*)(lp), 4, 0, 0)

// ---------------- W1 fragment pack + bcnt zero (fused, independent work) ----
// Wb[(c*64 + lane)*8 + i] = bf16(W1[k][col]), k = c*32 + (lane>>4)*8 + i, col = lane&15
__global__ void k_wpack_zero(const float* __restrict__ W1, short* __restrict__ Wb,
                             int* __restrict__ bcnt) {
  int t = blockIdx.x * blockDim.x + threadIdx.x;
  if (t < 16 * NBKT_MAX) bcnt[t] = 0;
  if (t >= NCH * 64 * 8) return;
  int i = t & 7, l = (t >> 3) & 63, c = t >> 9;
  int g = l >> 4, col = l & 15;
  int k = c * 32 + g * 8 + i;
  float v = (k < NF) ? W1[(size_t)k * NH + col] : 0.f;
  Wb[t] = (short)f2bf(v);
}

// ---------------- bucketed CSR build ----------------
__global__ __launch_bounds__(256) void k_bcount(const int* __restrict__ dst,
                                                int* __restrict__ bcnt,
                                                int E, int nbkt) {
  __shared__ int h[NBKT_MAX];
  int t = threadIdx.x;
  for (int i = t; i < nbkt; i += 256) h[i] = 0;
  __syncthreads();
  int e0 = blockIdx.x * SC_C;
  int e1 = min(E, e0 + SC_C);
  for (int e = e0 + t; e < e1; e += 256)
    atomicAdd(&h[((unsigned)dst[e]) >> 8], 1);
  __syncthreads();
  for (int i = t; i < nbkt; i += 256)
    if (h[i]) atomicAdd(&bcnt[i * 16], h[i]);
}

__global__ void k_bscan(const int* __restrict__ bcnt, int* __restrict__ bbase,
                        int* __restrict__ bfill, int nbkt) {
  __shared__ int sm[NBKT_MAX];
  int t = threadIdx.x;  // blockDim = NBKT_MAX
  int v = (t < nbkt) ? bcnt[t * 16] : 0;
  sm[t] = v;
  __syncthreads();
  for (int o = 1; o < NBKT_MAX; o <<= 1) {
    int u = (t >= o) ? sm[t - o] : 0;
    __syncthreads();
    sm[t] += u;
    __syncthreads();
  }
  if (t < nbkt) {
    int b = sm[t] - v;
    bbase[t] = b;
    bfill[t * 16] = b;
  }
  if (t == nbkt) bbase[nbkt] = sm[t];  // == E
}

__global__ __launch_bounds__(256) void k_bscatter(const int* __restrict__ ei,
                                                  int* __restrict__ bfill,
                                                  int* __restrict__ ebuf,
                                                  int E, int nbkt) {
  __shared__ int h[NBKT_MAX];              // hist, then fill cursor
  __shared__ int lo[NBKT_MAX];             // block-local exclusive base
  __shared__ int lb[NBKT_MAX];             // reserved global base
  __shared__ int sc2[256];
  __shared__ int sval[SC_C];
  __shared__ unsigned short sbkt[SC_C];
  const int* src = ei;
  const int* dst = ei + E;
  int t = threadIdx.x;
  for (int i = t; i < NBKT_MAX; i += 256) h[i] = 0;
  __syncthreads();
  int e0 = blockIdx.x * SC_C;
  int e1 = min(E, e0 + SC_C);
  int csize = e1 - e0;
  for (int e = e0 + t; e < e1; e += 256)
    atomicAdd(&h[((unsigned)dst[e]) >> 8], 1);
  __syncthreads();
  int base = 0;
#pragma unroll
  for (int j = 0; j < 2; ++j) {
    int idx = j * 256 + t;
    int v = h[idx];
    sc2[t] = v;
    __syncthreads();
    for (int o = 1; o < 256; o <<= 1) {
      int u = (t >= o) ? sc2[t - o] : 0;
      __syncthreads();
      sc2[t] += u;
      __syncthreads();
    }
    lo[idx] = base + sc2[t] - v;
    int tot = sc2[255];
    __syncthreads();
    base += tot;
  }
  for (int i = t; i < nbkt; i += 256) {
    int c = h[i];
    lb[i] = c ? atomicAdd(&bfill[i * 16], c) : 0;
    h[i] = 0;
  }
  __syncthreads();
  for (int e = e0 + t; e < e1; e += 256) {
    unsigned d = (unsigned)dst[e];
    int bk = d >> 8;
    int p = lo[bk] + atomicAdd(&h[bk], 1);
    sval[p] = (int)(((d & 255u) << 24) | (unsigned)src[e]);
    sbkt[p] = (unsigned short)bk;
  }
  __syncthreads();
  for (int i = t; i < csize; i += 256) {
    int bk = sbkt[i];
    ebuf[lb[bk] + (i - lo[bk])] = sval[i];
  }
}

__global__ __launch_bounds__(256) void k_bcsr(const int* __restrict__ ebuf,
                                              const int* __restrict__ bbase,
                                              int* __restrict__ off,
                                              int* __restrict__ srcs,
                                              float* __restrict__ dis, int n) {
  __shared__ int h[256];
  __shared__ int sc[256];
  int b = blockIdx.x, t = threadIdx.x;
  int eb = bbase[b], ee = bbase[b + 1];
  h[t] = 0;
  __syncthreads();
  for (int i = eb + t; i < ee; i += 256)
    atomicAdd(&h[((unsigned)ebuf[i]) >> 24], 1);
  __syncthreads();
  int deg = h[t];
  sc[t] = deg;
  __syncthreads();
  for (int o = 1; o < 256; o <<= 1) {
    int u = (t >= o) ? sc[t - o] : 0;
    __syncthreads();
    sc[t] += u;
    __syncthreads();
  }
  int excl = sc[t] - deg;
  int node = (b << 8) + t;
  if (node < n) {
    off[node] = eb + excl;
    dis[node] = rsqrtf((float)deg + 1.0f);
  }
  if (b == (int)gridDim.x - 1 && t == 0) off[n] = ee;
  h[t] = eb + excl;  // reuse as fill cursor
  __syncthreads();
  for (int i = eb + t; i < ee; i += 256) {
    unsigned v = (unsigned)ebuf[i];
    int slot = atomicAdd(&h[v >> 24], 1);
    srcs[slot] = (int)(v & 0xFFFFFFu);
  }
}

// ---------------- GEMM1: double-buffered async-DMA staging, no barriers ----
// hs1 = bf16( (x @ W1) * dis[row] ), [n][16] bf16 rows. Wave = 16 rows.
// Pipeline per chunk: vmcnt(0) [drains stage(c)+w(c), both needed now] ->
// issue stage(c+1) + w(c+1) -> compute(c). The 16 DMA loads of c+1 are in
// flight under compute(c) and the next drain -> latency hidden; per-wave
// in-flight ~4KB at ~80% duty. LDS 34.8KB/block -> 4 blocks/CU, 16 waves/CU.
__global__ __launch_bounds__(256) void k_gemm1(
    const float* __restrict__ x, const short* __restrict__ Wb,
    const float* __restrict__ dis, unsigned short* __restrict__ hs1, int n) {
  __shared__ float xs[4][2][16][68];  // [wave][buf][row][col(+pad)] 34.8KB
  int l = threadIdx.x & 63;
  int wv = threadIdx.x >> 6;
  int wid = (blockIdx.x << 2) + wv;
  int ntb = (n + 15) >> 4;
  if (wid >= ntb) return;          // no barriers in this kernel -> safe
  int row0 = wid << 4;
  int rl = l & 15, g = l >> 4;
  bool fast = (row0 + 15 < n);     // n % 16 == 0 -> always true in practice

  const bf16x8* wp = (const bf16x8*)Wb + l;
  f32x4 acc;
#pragma unroll
  for (int j = 0; j < 4; ++j) acc[j] = 0.f;

#define STAGE(CC, BB) do {                                                  \
    if (fast) {                                                             \
      const float* cb = x + (size_t)row0 * NF + (CC) * 64 + l;              \
      _Pragma("unroll") for (int r = 0; r < 16; ++r)                        \
        GLOAD(cb + (size_t)r * NF, &xs[wv][BB][r][0]);                      \
    } else {                                                                \
      _Pragma("unroll") for (int r = 0; r < 16; ++r) {                      \
        int rr = row0 + r; if (rr >= n) rr = n - 1;                         \
        GLOAD(x + (size_t)rr * NF + (CC) * 64 + l, &xs[wv][BB][r][0]);      \
      }                                                                     \
    }                                                                       \
  } while (0)

  STAGE(0, 0);
  bf16x8 w0 = wp[0];
  bf16x8 w1 = wp[64];

  for (int c = 0; c < NFC; ++c) {
    asm volatile("s_waitcnt vmcnt(0)" ::: "memory");  // stage(c)+w(c) ready
    bf16x8 nw0, nw1;
    if (c + 1 < NFC) {
      STAGE(c + 1, (c + 1) & 1);                      // 16 DMAs in flight
      nw0 = wp[(size_t)(2 * c + 2) * 64];             // next W in flight
      nw1 = wp[(size_t)(2 * c + 3) * 64];
    }
    // compute chunk c from buf c&1 (overlaps with the in-flight loads)
    const int bb = c & 1;
#pragma unroll
    for (int ks = 0; ks < 2; ++ks) {
      const float4* p = (const float4*)&xs[wv][bb][rl][ks * 32 + g * 8];
      float4 a0 = p[0], a1 = p[1];
      bf16x8 af;
      af[0] = f2bfs(a0.x); af[1] = f2bfs(a0.y);
      af[2] = f2bfs(a0.z); af[3] = f2bfs(a0.w);
      af[4] = f2bfs(a1.x); af[5] = f2bfs(a1.y);
      af[6] = f2bfs(a1.z); af[7] = f2bfs(a1.w);
      acc = __builtin_amdgcn_mfma_f32_16x16x32_bf16(af, ks ? w1 : w0,
                                                    acc, 0, 0, 0);
    }
    if (c + 1 < NFC) { w0 = nw0; w1 = nw1; }
  }
#undef STAGE

  // K tail: cols 1408..1432 via guarded register loads (A row = lane&15)
  {
    int rr = row0 + rl;
    if (rr >= n) rr = n - 1;
    const float* xp = x + (size_t)rr * NF;
    bf16x8 wt = wp[(size_t)(NCH - 1) * 64];
    bf16x8 at;
#pragma unroll
    for (int i = 0; i < 8; ++i) {
      int k = NFC * 64 + g * 8 + i;
      at[i] = (k < NF) ? f2bfs(xp[k]) : (short)0;
    }
    acc = __builtin_amdgcn_mfma_f32_16x16x32_bf16(at, wt, acc, 0, 0, 0);
  }

  // D layout (m89): col = lane&15, row_in_tile = (lane>>4)*4 + reg
#pragma unroll
  for (int rr = 0; rr < 4; ++rr) {
    int row = row0 + g * 4 + rr;
    if (row < n) hs1[(size_t)row * NH + rl] = f2bf(acc[rr] * dis[row]);
  }
}

// ---------------- pull layer 1 + bias + relu + GEMM2 fused (16 lanes/node) --
__global__ __launch_bounds__(256) void k_pull1(
    const int* __restrict__ off, const int* __restrict__ srcs,
    const float* __restrict__ dis, const uint4* __restrict__ hs1,
    const float* __restrict__ b1, const float* __restrict__ W2,
    uint4* __restrict__ hs2, int n) {
  int t = blockIdx.x * blockDim.x + threadIdx.x;
  int d = t >> 4;
  if (d >= n) return;
  int sub = t & 15, half = sub & 1, ph = sub >> 1;  // ph in [0,8)

  float a[8] = {0.f, 0.f, 0.f, 0.f, 0.f, 0.f, 0.f, 0.f};
  if (ph == 0) acc8(a, hs1[(size_t)d * 2 + half]);  // self loop, once per half

  int k = off[d] + ph, k1 = off[d + 1];
  for (; k + 8 < k1; k += 16) {  // 2 independent gathers in flight
    int s0 = srcs[k], s1 = srcs[k + 8];
    uint4 r0 = hs1[(size_t)s0 * 2 + half];
    uint4 r1 = hs1[(size_t)s1 * 2 + half];
    acc8(a, r0);
    acc8(a, r1);
  }
  if (k < k1) acc8(a, hs1[(size_t)srcs[k] * 2 + half]);

#pragma unroll
  for (int i = 0; i < 8; ++i) {  // reduce over the 8 phases (lane bits 1..3)
    a[i] += __shfl_xor(a[i], 2);
    a[i] += __shfl_xor(a[i], 4);
    a[i] += __shfl_xor(a[i], 8);
  }

  float dd = dis[d];
  float v[8];
#pragma unroll
  for (int i = 0; i < 8; ++i) v[i] = fmaxf(a[i] * dd + b1[half * 8 + i], 0.f);
  float p[NC];
#pragma unroll
  for (int c = 0; c < NC; ++c) {
    float s = 0.f;
#pragma unroll
    for (int i = 0; i < 8; ++i) s = fmaf(v[i], W2[(half * 8 + i) * NC + c], s);
    p[c] = s;
  }
#pragma unroll
  for (int c = 0; c < NC; ++c) p[c] += __shfl_xor(p[c], 1);  // combine halves
  if (sub == 0) {
    uint4 o;
    o.x = packbf(p[0] * dd, p[1] * dd);
    o.y = packbf(p[2] * dd, p[3] * dd);
    o.z = packbf(p[4] * dd, p[5] * dd);
    o.w = packbf(p[6] * dd, 0.f);  // pad col
    hs2[d] = o;
  }
}

// ---------------- pull layer 2 + bias + relu + log_softmax (8 lanes/node) ---
__global__ __launch_bounds__(256) void k_pull2(
    const int* __restrict__ off, const int* __restrict__ srcs,
    const float* __restrict__ dis, const uint4* __restrict__ hs2,
    const float* __restrict__ b2, float* __restrict__ out, int n) {
  int t = blockIdx.x * blockDim.x + threadIdx.x;
  int d = t >> 3;
  if (d >= n) return;
  int ph = t & 7;

  float a[8] = {0.f, 0.f, 0.f, 0.f, 0.f, 0.f, 0.f, 0.f};
  if (ph == 0) acc8(a, hs2[d]);  // self loop once

  int k = off[d] + ph, k1 = off[d + 1];
  for (; k + 8 < k1; k += 16) {
    int s0 = srcs[k], s1 = srcs[k + 8];
    uint4 r0 = hs2[s0];
    uint4 r1 = hs2[s1];
    acc8(a, r0);
    acc8(a, r1);
  }
  if (k < k1) acc8(a, hs2[srcs[k]]);

#pragma unroll
  for (int i = 0; i < 8; ++i) {  // reduce across the 8 phase lanes
    a[i] += __shfl_xor(a[i], 1);
    a[i] += __shfl_xor(a[i], 2);
    a[i] += __shfl_xor(a[i], 4);
  }
  float dd = dis[d];
  float u[NC];
#pragma unroll
  for (int c = 0; c < NC; ++c) u[c] = fmaxf(a[c] * dd + b2[c], 0.f);
  float m = u[0];
#pragma unroll
  for (int c = 1; c < NC; ++c) m = fmaxf(m, u[c]);
  float sum = 0.f;
#pragma unroll
  for (int c = 0; c < NC; ++c) sum += expf(u[c] - m);
  float lg = logf(sum);
  if (ph < NC) out[(size_t)d * NC + ph] = u[ph] - m - lg;
}

extern "C" void kernel_launch(void* const* d_in, const int* in_sizes, int n_in,
                              void* d_out, int out_size, void* d_ws, size_t ws_size,
                              hipStream_t stream) {
  const float* x  = (const float*)d_in[0];
  const int*   ei = (const int*)d_in[1];
  const float* W1 = (const float*)d_in[2];
  const float* b1 = (const float*)d_in[3];
  const float* W2 = (const float*)d_in[4];
  const float* b2 = (const float*)d_in[5];
  int n = in_sizes[0] / NF;   // 100000
  int E = in_sizes[1] / 2;    // 3200000
  int nbkt = (n + 255) >> 8;  // 391

  // workspace layout (each region 16B-aligned)
  char* w = (char*)d_ws;
#define TAKE(ptrty, name, bytes) \
  ptrty name = (ptrty)w; w += ((size_t)(bytes) + 15) & ~(size_t)15;
  TAKE(unsigned short*, hs1,  sizeof(short) * (size_t)n * NH)
  TAKE(uint4*,          hs2,  16 * (size_t)n)
  TAKE(float*,          dis,  sizeof(float) * n)
  TAKE(short*,          Wb,   sizeof(short) * NCH * 64 * 8)
  TAKE(int*,            bcnt, sizeof(int) * 16 * NBKT_MAX)
  TAKE(int*,            bfill,sizeof(int) * 16 * NBKT_MAX)
  TAKE(int*,            bbase,sizeof(int) * (NBKT_MAX + 1))
  TAKE(int*,            ebuf, sizeof(int) * (size_t)E)
  TAKE(int*,            off,  sizeof(int) * (n + 1))
  TAKE(int*,            srcs, sizeof(int) * (size_t)E)
#undef TAKE
  float* out = (float*)d_out;

  int nsb = (E + SC_C - 1) / SC_C;  // 1042

  // independent prep (also zeroes bcnt)
  k_wpack_zero<<<(NCH * 64 * 8 + 255) / 256, 256, 0, stream>>>(W1, Wb, bcnt);

  // bucketed CSR build
  k_bcount<<<nsb, 256, 0, stream>>>(ei + E, bcnt, E, nbkt);
  k_bscan<<<1, NBKT_MAX, 0, stream>>>(bcnt, bbase, bfill, nbkt);
  k_bscatter<<<nsb, 256, 0, stream>>>(ei, bfill, ebuf, E, nbkt);
  k_bcsr<<<nbkt, 256, 0, stream>>>(ebuf, bbase, off, srcs, dis, n);

  // features
  int ntb = (n + 15) >> 4;  // 6250 wave-tiles
  int gblocks = (ntb + 3) / 4;
  k_gemm1<<<gblocks, 256, 0, stream>>>(x, Wb, dis, hs1, n);
  k_pull1<<<((size_t)n * 16 + 255) / 256, 256, 0, stream>>>(
      off, srcs, dis, (const uint4*)hs1, b1, W2, hs2, n);
  k_pull2<<<((size_t)n * 8 + 255) / 256, 256, 0, stream>>>(
      off, srcs, dis, hs2, b2, out, n);
}

// Round 13
// 293.587 us; speedup vs baseline: 1.5180x; 1.0789x over previous
//
#include <hip/hip_runtime.h>
#include <hip/hip_bf16.h>
#include <math.h>

#define NF 1433
#define NH 16
#define NC 7
#define NCH 45          // ceil(1433/32) 32-col K-chunks (Wb layout)
#define NBKT_MAX 512    // supports n <= 131072 (bucket = dst>>8)
#define SC_C 3072       // edges per bscatter block (LDS-sortable chunk)
#define XSTR 772        // LDS row stride (dwords): 16B-aligned, 2-way bank alias

typedef __attribute__((ext_vector_type(8))) short bf16x8;
typedef __attribute__((ext_vector_type(4))) float f32x4;

__device__ __forceinline__ unsigned short f2bf(float f) {
  unsigned int u = __float_as_uint(f);
  unsigned int r = (u + 0x7FFFu + ((u >> 16) & 1u)) >> 16;  // RNE
  return (unsigned short)r;
}
// hot-path convert (compiler folds pairs into v_cvt_pk_bf16_f32)
__device__ __forceinline__ short f2bfs(float f) {
  union { __hip_bfloat16 h; short s; } u;
  u.h = __float2bfloat16(f);
  return u.s;
}
__device__ __forceinline__ unsigned int packbf(float lo, float hi) {
  return (unsigned int)f2bf(lo) | ((unsigned int)f2bf(hi) << 16);
}
// accumulate 8 bf16 (packed in uint4) into a[0..7]
__device__ __forceinline__ void acc8(float* a, uint4 r) {
  a[0] += __uint_as_float(r.x << 16); a[1] += __uint_as_float(r.x & 0xffff0000u);
  a[2] += __uint_as_float(r.y << 16); a[3] += __uint_as_float(r.y & 0xffff0000u);
  a[4] += __uint_as_float(r.z << 16); a[5] += __uint_as_float(r.z & 0xffff0000u);
  a[6] += __uint_as_float(r.w << 16); a[7] += __uint_as_float(r.w & 0xffff0000u);
}

// async global->LDS DMA, 4B/lane: LDS dest is wave-uniform base + lane*4,
// global src is per-lane (m104/m108 contract).
#define GLOAD(gp, lp) __builtin_amdgcn_global_load_lds(                     \
    (const __attribute__((address_space(1))) void*)(gp),                    \
    (__attribute__((address_space(3))) void*)(lp), 4, 0, 0)

// ---------------- W1 fragment pack + bcnt zero (fused, independent work) ----
// Wb[(c*64 + lane)*8 + i] = bf16(W1[k][col]), k = c*32 + (lane>>4)*8 + i, col = lane&15
__global__ void k_wpack_zero(const float* __restrict__ W1, short* __restrict__ Wb,
                             int* __restrict__ bcnt) {
  int t = blockIdx.x * blockDim.x + threadIdx.x;
  if (t < 16 * NBKT_MAX) bcnt[t] = 0;
  if (t >= NCH * 64 * 8) return;
  int i = t & 7, l = (t >> 3) & 63, c = t >> 9;
  int g = l >> 4, col = l & 15;
  int k = c * 32 + g * 8 + i;
  float v = (k < NF) ? W1[(size_t)k * NH + col] : 0.f;
  Wb[t] = (short)f2bf(v);
}

// ---------------- bucketed CSR build ----------------
__global__ __launch_bounds__(256) void k_bcount(const int* __restrict__ dst,
                                                int* __restrict__ bcnt,
                                                int E, int nbkt) {
  __shared__ int h[NBKT_MAX];
  int t = threadIdx.x;
  for (int i = t; i < nbkt; i += 256) h[i] = 0;
  __syncthreads();
  int e0 = blockIdx.x * SC_C;
  int e1 = min(E, e0 + SC_C);
  for (int e = e0 + t; e < e1; e += 256)
    atomicAdd(&h[((unsigned)dst[e]) >> 8], 1);
  __syncthreads();
  for (int i = t; i < nbkt; i += 256)
    if (h[i]) atomicAdd(&bcnt[i * 16], h[i]);
}

__global__ void k_bscan(const int* __restrict__ bcnt, int* __restrict__ bbase,
                        int* __restrict__ bfill, int nbkt) {
  __shared__ int sm[NBKT_MAX];
  int t = threadIdx.x;  // blockDim = NBKT_MAX
  int v = (t < nbkt) ? bcnt[t * 16] : 0;
  sm[t] = v;
  __syncthreads();
  for (int o = 1; o < NBKT_MAX; o <<= 1) {
    int u = (t >= o) ? sm[t - o] : 0;
    __syncthreads();
    sm[t] += u;
    __syncthreads();
  }
  if (t < nbkt) {
    int b = sm[t] - v;
    bbase[t] = b;
    bfill[t * 16] = b;
  }
  if (t == nbkt) bbase[nbkt] = sm[t];  // == E
}

__global__ __launch_bounds__(256) void k_bscatter(const int* __restrict__ ei,
                                                  int* __restrict__ bfill,
                                                  int* __restrict__ ebuf,
                                                  int E, int nbkt) {
  __shared__ int h[NBKT_MAX];              // hist, then fill cursor
  __shared__ int lo[NBKT_MAX];             // block-local exclusive base
  __shared__ int lb[NBKT_MAX];             // reserved global base
  __shared__ int sc2[256];
  __shared__ int sval[SC_C];
  __shared__ unsigned short sbkt[SC_C];
  const int* src = ei;
  const int* dst = ei + E;
  int t = threadIdx.x;
  for (int i = t; i < NBKT_MAX; i += 256) h[i] = 0;
  __syncthreads();
  int e0 = blockIdx.x * SC_C;
  int e1 = min(E, e0 + SC_C);
  int csize = e1 - e0;
  for (int e = e0 + t; e < e1; e += 256)
    atomicAdd(&h[((unsigned)dst[e]) >> 8], 1);
  __syncthreads();
  int base = 0;
#pragma unroll
  for (int j = 0; j < 2; ++j) {
    int idx = j * 256 + t;
    int v = h[idx];
    sc2[t] = v;
    __syncthreads();
    for (int o = 1; o < 256; o <<= 1) {
      int u = (t >= o) ? sc2[t - o] : 0;
      __syncthreads();
      sc2[t] += u;
      __syncthreads();
    }
    lo[idx] = base + sc2[t] - v;
    int tot = sc2[255];
    __syncthreads();
    base += tot;
  }
  for (int i = t; i < nbkt; i += 256) {
    int c = h[i];
    lb[i] = c ? atomicAdd(&bfill[i * 16], c) : 0;
    h[i] = 0;
  }
  __syncthreads();
  for (int e = e0 + t; e < e1; e += 256) {
    unsigned d = (unsigned)dst[e];
    int bk = d >> 8;
    int p = lo[bk] + atomicAdd(&h[bk], 1);
    sval[p] = (int)(((d & 255u) << 24) | (unsigned)src[e]);
    sbkt[p] = (unsigned short)bk;
  }
  __syncthreads();
  for (int i = t; i < csize; i += 256) {
    int bk = sbkt[i];
    ebuf[lb[bk] + (i - lo[bk])] = sval[i];
  }
}

__global__ __launch_bounds__(256) void k_bcsr(const int* __restrict__ ebuf,
                                              const int* __restrict__ bbase,
                                              int* __restrict__ off,
                                              int* __restrict__ srcs,
                                              float* __restrict__ dis, int n) {
  __shared__ int h[256];
  __shared__ int sc[256];
  int b = blockIdx.x, t = threadIdx.x;
  int eb = bbase[b], ee = bbase[b + 1];
  h[t] = 0;
  __syncthreads();
  for (int i = eb + t; i < ee; i += 256)
    atomicAdd(&h[((unsigned)ebuf[i]) >> 24], 1);
  __syncthreads();
  int deg = h[t];
  sc[t] = deg;
  __syncthreads();
  for (int o = 1; o < 256; o <<= 1) {
    int u = (t >= o) ? sc[t - o] : 0;
    __syncthreads();
    sc[t] += u;
    __syncthreads();
  }
  int excl = sc[t] - deg;
  int node = (b << 8) + t;
  if (node < n) {
    off[node] = eb + excl;
    dis[node] = rsqrtf((float)deg + 1.0f);
  }
  if (b == (int)gridDim.x - 1 && t == 0) off[n] = ee;
  h[t] = eb + excl;  // reuse as fill cursor
  __syncthreads();
  for (int i = eb + t; i < ee; i += 256) {
    unsigned v = (unsigned)ebuf[i];
    int slot = atomicAdd(&h[v >> 24], 1);
    srcs[slot] = (int)(v & 0xFFFFFFu);
  }
}

// ---------------- GEMM1: full-row staged, 16 rows/block, 4 waves split K ----
// hs1 = bf16( (x @ W1) * dis[row] ), [n][16] bf16 rows.
// DRAM-burst fix: each row staged as 12 consecutive 256B DMAs (3KB sequential
// stream) per mega-chunk, vs 256B/row-visit before. Two mega-chunks
// (cols 0..767, 768..1432). Waves take K-chunks c%4==wv; LDS reduce at end.
__global__ __launch_bounds__(256) void k_gemm1(
    const float* __restrict__ x, const short* __restrict__ Wb,
    const float* __restrict__ dis, unsigned short* __restrict__ hs1, int n) {
  __shared__ float xs[16][XSTR];   // 49.4 KB -> 3 blocks/CU
  int t = threadIdx.x;
  int l = t & 63, wv = t >> 6;
  int row0 = blockIdx.x << 4;
  int rl = l & 15, g = l >> 4;

  const bf16x8* wp = (const bf16x8*)Wb + l;
  f32x4 acc;
#pragma unroll
  for (int j = 0; j < 4; ++j) acc[j] = 0.f;

  int myrow[4];
#pragma unroll
  for (int r = 0; r < 4; ++r) {
    int row = row0 + 4 * wv + r;
    myrow[r] = (row < n) ? row : (n - 1);  // clamp; masked at store
  }

  // ---- stage mega0: cols 0..767, 12 consecutive 256B DMAs per row ----
#pragma unroll
  for (int r = 0; r < 4; ++r) {
    const float* rp = x + (size_t)myrow[r] * NF;
#pragma unroll
    for (int j = 0; j < 12; ++j)
      GLOAD(rp + j * 64 + l, &xs[4 * wv + r][j * 64]);
  }
  asm volatile("s_waitcnt vmcnt(0)" ::: "memory");
  __syncthreads();

  // ---- compute mega0: chunks wv+4i, i=0..5 (cols c*32 .. c*32+31) ----
#pragma unroll
  for (int i = 0; i < 6; ++i) {
    int c = wv + 4 * i;
    bf16x8 w = wp[(size_t)c * 64];
    const float4* p = (const float4*)&xs[rl][c * 32 + g * 8];
    float4 a0 = p[0], a1 = p[1];
    bf16x8 af;
    af[0] = f2bfs(a0.x); af[1] = f2bfs(a0.y);
    af[2] = f2bfs(a0.z); af[3] = f2bfs(a0.w);
    af[4] = f2bfs(a1.x); af[5] = f2bfs(a1.y);
    af[6] = f2bfs(a1.z); af[7] = f2bfs(a1.w);
    acc = __builtin_amdgcn_mfma_f32_16x16x32_bf16(af, w, acc, 0, 0, 0);
  }
  __syncthreads();  // all reads of mega0 complete before overwrite

  // ---- stage mega1: cols 768..1432 (10 full + 1 overlapped tail per row) --
#pragma unroll
  for (int r = 0; r < 4; ++r) {
    const float* rp = x + (size_t)myrow[r] * NF;
#pragma unroll
    for (int j = 0; j < 10; ++j)
      GLOAD(rp + 768 + j * 64 + l, &xs[4 * wv + r][j * 64]);
    // cols 1369..1432 -> rel 601..664 (overlap region rewritten w/ same data)
    GLOAD(rp + (NF - 64) + l, &xs[4 * wv + r][NF - 64 - 768]);
  }
  // zero rel cols 665..671 (chunk-44 pad; Wb is 0 there, avoid NaN*0)
  if (l < 28) xs[4 * wv + (l / 7)][665 + (l % 7)] = 0.f;
  asm volatile("s_waitcnt vmcnt(0)" ::: "memory");
  __syncthreads();

  // ---- compute mega1: chunks 24+wv+4i < 45 ----
#pragma unroll
  for (int i = 0; i < 6; ++i) {
    int c = 24 + wv + 4 * i;
    if (c < NCH) {
      bf16x8 w = wp[(size_t)c * 64];
      const float4* p = (const float4*)&xs[rl][(c - 24) * 32 + g * 8];
      float4 a0 = p[0], a1 = p[1];
      bf16x8 af;
      af[0] = f2bfs(a0.x); af[1] = f2bfs(a0.y);
      af[2] = f2bfs(a0.z); af[3] = f2bfs(a0.w);
      af[4] = f2bfs(a1.x); af[5] = f2bfs(a1.y);
      af[6] = f2bfs(a1.z); af[7] = f2bfs(a1.w);
      acc = __builtin_amdgcn_mfma_f32_16x16x32_bf16(af, w, acc, 0, 0, 0);
    }
  }
  __syncthreads();  // done reading x data; reuse xs for partials

  // ---- cross-wave reduce: ps[wave][16 rows][16 cols] ----
  float* ps = &xs[0][0];  // 4 KB
  // D layout (m89): col = lane&15, row_in_tile = (lane>>4)*4 + reg
#pragma unroll
  for (int r = 0; r < 4; ++r)
    ps[(wv * 16 + g * 4 + r) * 16 + rl] = acc[r];
  __syncthreads();
  if (wv == 0) {
    int row = l >> 2, c0 = (l & 3) * 4;
    float4 s0 = *(const float4*)&ps[(row) * 16 + c0];
    float4 s1 = *(const float4*)&ps[(16 + row) * 16 + c0];
    float4 s2 = *(const float4*)&ps[(32 + row) * 16 + c0];
    float4 s3 = *(const float4*)&ps[(48 + row) * 16 + c0];
    int grow = row0 + row;
    if (grow < n) {
      float dd = dis[grow];
      ushort4 o;
      o.x = f2bf((s0.x + s1.x + s2.x + s3.x) * dd);
      o.y = f2bf((s0.y + s1.y + s2.y + s3.y) * dd);
      o.z = f2bf((s0.z + s1.z + s2.z + s3.z) * dd);
      o.w = f2bf((s0.w + s1.w + s2.w + s3.w) * dd);
      *(ushort4*)(hs1 + (size_t)grow * NH + c0) = o;
    }
  }
}

// ---------------- pull layer 1 + bias + relu + GEMM2 fused (16 lanes/node) --
__global__ __launch_bounds__(256) void k_pull1(
    const int* __restrict__ off, const int* __restrict__ srcs,
    const float* __restrict__ dis, const uint4* __restrict__ hs1,
    const float* __restrict__ b1, const float* __restrict__ W2,
    uint4* __restrict__ hs2, int n) {
  int t = blockIdx.x * blockDim.x + threadIdx.x;
  int d = t >> 4;
  if (d >= n) return;
  int sub = t & 15, half = sub & 1, ph = sub >> 1;  // ph in [0,8)

  float a[8] = {0.f, 0.f, 0.f, 0.f, 0.f, 0.f, 0.f, 0.f};
  if (ph == 0) acc8(a, hs1[(size_t)d * 2 + half]);  // self loop, once per half

  int k = off[d] + ph, k1 = off[d + 1];
  for (; k + 8 < k1; k += 16) {  // 2 independent gathers in flight
    int s0 = srcs[k], s1 = srcs[k + 8];
    uint4 r0 = hs1[(size_t)s0 * 2 + half];
    uint4 r1 = hs1[(size_t)s1 * 2 + half];
    acc8(a, r0);
    acc8(a, r1);
  }
  if (k < k1) acc8(a, hs1[(size_t)srcs[k] * 2 + half]);

#pragma unroll
  for (int i = 0; i < 8; ++i) {  // reduce over the 8 phases (lane bits 1..3)
    a[i] += __shfl_xor(a[i], 2);
    a[i] += __shfl_xor(a[i], 4);
    a[i] += __shfl_xor(a[i], 8);
  }

  float dd = dis[d];
  float v[8];
#pragma unroll
  for (int i = 0; i < 8; ++i) v[i] = fmaxf(a[i] * dd + b1[half * 8 + i], 0.f);
  float p[NC];
#pragma unroll
  for (int c = 0; c < NC; ++c) {
    float s = 0.f;
#pragma unroll
    for (int i = 0; i < 8; ++i) s = fmaf(v[i], W2[(half * 8 + i) * NC + c], s);
    p[c] = s;
  }
#pragma unroll
  for (int c = 0; c < NC; ++c) p[c] += __shfl_xor(p[c], 1);  // combine halves
  if (sub == 0) {
    uint4 o;
    o.x = packbf(p[0] * dd, p[1] * dd);
    o.y = packbf(p[2] * dd, p[3] * dd);
    o.z = packbf(p[4] * dd, p[5] * dd);
    o.w = packbf(p[6] * dd, 0.f);  // pad col
    hs2[d] = o;
  }
}

// ---------------- pull layer 2 + bias + relu + log_softmax (8 lanes/node) ---
__global__ __launch_bounds__(256) void k_pull2(
    const int* __restrict__ off, const int* __restrict__ srcs,
    const float* __restrict__ dis, const uint4* __restrict__ hs2,
    const float* __restrict__ b2, float* __restrict__ out, int n) {
  int t = blockIdx.x * blockDim.x + threadIdx.x;
  int d = t >> 3;
  if (d >= n) return;
  int ph = t & 7;

  float a[8] = {0.f, 0.f, 0.f, 0.f, 0.f, 0.f, 0.f, 0.f};
  if (ph == 0) acc8(a, hs2[d]);  // self loop once

  int k = off[d] + ph, k1 = off[d + 1];
  for (; k + 8 < k1; k += 16) {
    int s0 = srcs[k], s1 = srcs[k + 8];
    uint4 r0 = hs2[s0];
    uint4 r1 = hs2[s1];
    acc8(a, r0);
    acc8(a, r1);
  }
  if (k < k1) acc8(a, hs2[srcs[k]]);

#pragma unroll
  for (int i = 0; i < 8; ++i) {  // reduce across the 8 phase lanes
    a[i] += __shfl_xor(a[i], 1);
    a[i] += __shfl_xor(a[i], 2);
    a[i] += __shfl_xor(a[i], 4);
  }
  float dd = dis[d];
  float u[NC];
#pragma unroll
  for (int c = 0; c < NC; ++c) u[c] = fmaxf(a[c] * dd + b2[c], 0.f);
  float m = u[0];
#pragma unroll
  for (int c = 1; c < NC; ++c) m = fmaxf(m, u[c]);
  float sum = 0.f;
#pragma unroll
  for (int c = 0; c < NC; ++c) sum += expf(u[c] - m);
  float lg = logf(sum);
  if (ph < NC) out[(size_t)d * NC + ph] = u[ph] - m - lg;
}

extern "C" void kernel_launch(void* const* d_in, const int* in_sizes, int n_in,
                              void* d_out, int out_size, void* d_ws, size_t ws_size,
                              hipStream_t stream) {
  const float* x  = (const float*)d_in[0];
  const int*   ei = (const int*)d_in[1];
  const float* W1 = (const float*)d_in[2];
  const float* b1 = (const float*)d_in[3];
  const float* W2 = (const float*)d_in[4];
  const float* b2 = (const float*)d_in[5];
  int n = in_sizes[0] / NF;   // 100000
  int E = in_sizes[1] / 2;    // 3200000
  int nbkt = (n + 255) >> 8;  // 391

  // workspace layout (each region 16B-aligned)
  char* w = (char*)d_ws;
#define TAKE(ptrty, name, bytes) \
  ptrty name = (ptrty)w; w += ((size_t)(bytes) + 15) & ~(size_t)15;
  TAKE(unsigned short*, hs1,  sizeof(short) * (size_t)n * NH)
  TAKE(uint4*,          hs2,  16 * (size_t)n)
  TAKE(float*,          dis,  sizeof(float) * n)
  TAKE(short*,          Wb,   sizeof(short) * NCH * 64 * 8)
  TAKE(int*,            bcnt, sizeof(int) * 16 * NBKT_MAX)
  TAKE(int*,            bfill,sizeof(int) * 16 * NBKT_MAX)
  TAKE(int*,            bbase,sizeof(int) * (NBKT_MAX + 1))
  TAKE(int*,            ebuf, sizeof(int) * (size_t)E)
  TAKE(int*,            off,  sizeof(int) * (n + 1))
  TAKE(int*,            srcs, sizeof(int) * (size_t)E)
#undef TAKE
  float* out = (float*)d_out;

  int nsb = (E + SC_C - 1) / SC_C;  // 1042

  // independent prep (also zeroes bcnt)
  k_wpack_zero<<<(NCH * 64 * 8 + 255) / 256, 256, 0, stream>>>(W1, Wb, bcnt);

  // bucketed CSR build
  k_bcount<<<nsb, 256, 0, stream>>>(ei + E, bcnt, E, nbkt);
  k_bscan<<<1, NBKT_MAX, 0, stream>>>(bcnt, bbase, bfill, nbkt);
  k_bscatter<<<nsb, 256, 0, stream>>>(ei, bfill, ebuf, E, nbkt);
  k_bcsr<<<nbkt, 256, 0, stream>>>(ebuf, bbase, off, srcs, dis, n);

  // features
  k_gemm1<<<(n + 15) / 16, 256, 0, stream>>>(x, Wb, dis, hs1, n);
  k_pull1<<<((size_t)n * 16 + 255) / 256, 256, 0, stream>>>(
      off, srcs, dis, (const uint4*)hs1, b1, W2, hs2, n);
  k_pull2<<<((size_t)n * 8 + 255) / 256, 256, 0, stream>>>(
      off, srcs, dis, hs2, b2, out, n);
}